// Round 8
// baseline (136.163 us; speedup 1.0000x reference)
//
#include <hip/hip_runtime.h>

typedef __attribute__((ext_vector_type(4))) float f32x4;
typedef __attribute__((ext_vector_type(8))) short bf16x8;

#define T_LEN 2048
#define ENC   512
#define DEC   1024
#define ATT   128
#define NB    64
#define BM    256            // rows per block (8 waves x 32)
#define NTB   (T_LEN / BM)   // 8 tiles per batch
#define NSTEP 17             // 16 keys K-steps + 1 conv-tap step

typedef unsigned int u32;
typedef __attribute__((address_space(1))) const u32 gu32;
typedef __attribute__((address_space(3))) u32 lu32;

__device__ __forceinline__ void async_copy16(const void* g, void* l) {
  __builtin_amdgcn_global_load_lds((gu32*)g, (lu32*)l, 16, 0, 0);
}

__device__ __forceinline__ unsigned short f2bf_rne(float x) {
  unsigned int u = __builtin_bit_cast(unsigned int, x);
  u += 0x7fff + ((u >> 16) & 1);
  return (unsigned short)(u >> 16);
}
// round-half-up: same 0.5-ulp max error, 2 VALU ops
__device__ __forceinline__ short f2bf_fast(float x) {
  unsigned int u = __builtin_bit_cast(unsigned int, x);
  return (short)((u + 0x8000u) >> 16);
}

__device__ __forceinline__ float fast_tanh(float x) {
  float e = __expf(2.f * x);
  return 1.f - 2.f / (e + 1.f);    // robust at +-inf
}

// ---------------- prep: pq = query@W2 (blocks 0..63); Bl frag-exact (blocks 64..191)
// Bl layout (shorts): (((t*8 + n)*64 + grp*16 + rsel)*8 + j)
//   where k = t*32 + grp*8 + j  (t<17, grp<4, j<8), col = n*16 + rsel.
// -> per (t,n) the 64 lanes' 16B frags are lane-contiguous (conflict-free ds_read_b128,
//    identity-mapped global_load_lds staging).
__global__ __launch_bounds__(128) void prep(
    const float* __restrict__ query, const float* __restrict__ W2,
    const float* __restrict__ W1, const float* __restrict__ convw,
    const float* __restrict__ ldense,
    float* __restrict__ pq, unsigned short* __restrict__ Bl) {
  int bidx = blockIdx.x;
  if (bidx < NB) {
    int a = threadIdx.x;
    const float* q = query + bidx * DEC;
    float a0 = 0.f, a1 = 0.f, a2 = 0.f, a3 = 0.f;
    for (int d = 0; d < DEC; d += 4) {
      a0 += q[d]     * W2[(d)     * ATT + a];
      a1 += q[d + 1] * W2[(d + 1) * ATT + a];
      a2 += q[d + 2] * W2[(d + 2) * ATT + a];
      a3 += q[d + 3] * W2[(d + 3) * ATT + a];
    }
    pq[bidx * ATT + a] = (a0 + a1) + (a2 + a3);
  } else {
    int a = bidx - NB;                   // output column 0..127
    int n = a >> 4, rs = a & 15;
    for (int k = threadIdx.x; k < NSTEP * 32; k += 128) {
      float v = 0.f;
      if (k < 512) {
        v = W1[k * ATT + a];
      } else if (k < 543) {
        int kc = k - 512;
        #pragma unroll
        for (int f = 0; f < 32; ++f) v += convw[f * 31 + kc] * ldense[f * ATT + a];
      }
      int t = k >> 5, g = (k & 31) >> 3, j = k & 7;
      Bl[(((t * 8 + n) * 64 + g * 16 + rs) << 3) + j] = f2bf_rne(v);
    }
  }
}

// ---------------- main: B fully LDS-resident, barrier-free K-loop, A global->reg
__global__ __launch_bounds__(512, 2) void lsa_main(
    const float* __restrict__ keys, const float* __restrict__ prev,
    const int* __restrict__ mask, const unsigned short* __restrict__ Bl,
    const float* __restrict__ pq, const float* __restrict__ Vv,
    float* __restrict__ wout, float* __restrict__ dpart, float* __restrict__ cpart) {
  __shared__ unsigned short Bsh[NSTEP * 4096];   // 139264 B, frag-exact layout
  __shared__ float e_vals[BM];                   // 1 KB

  const int tid = threadIdx.x;
  const int bid = blockIdx.x;
  const int b = bid >> 3;
  const int trow0 = (bid & 7) * BM;
  const int lane = tid & 63;
  const int w = tid >> 6;                        // 8 waves, wave owns rows w*32..+32
  const int rsel = lane & 15, grp = lane >> 4;
  const int row0 = trow0 + w * 32;

  // A source: rows row0 + m*16 + rsel, k = t*32 + grp*8 .. +8 (two f32x4)
  const float* keyrow = keys + ((size_t)b * T_LEN + row0 + rsel) * ENC + grp * 8;

  f32x4 acc[2][8];
  #pragma unroll
  for (int m = 0; m < 2; ++m)
    #pragma unroll
    for (int n = 0; n < 8; ++n) acc[m][n] = (f32x4)0.f;

  // ---- prologue: issue A(0) loads, stage ALL of B (17 x 8 KB identity), one barrier ----
  f32x4 aP[2][2], aQ[2][2];
  #pragma unroll
  for (int m = 0; m < 2; ++m) {
    aP[m][0] = *(const f32x4*)(keyrow + m * 16 * ENC);
    aP[m][1] = *(const f32x4*)(keyrow + m * 16 * ENC + 4);
  }
  {
    const char* src = (const char*)Bl + w * 1024 + lane * 16;
    char* dst = (char*)Bsh + w * 1024;
    #pragma unroll
    for (int s = 0; s < NSTEP; ++s)
      async_copy16(src + s * 8192, dst + s * 8192);
  }
  __syncthreads();   // drains vmcnt: B resident, aP complete

  // ---- K-loop: NO barriers. 1-deep reg pipeline; sched_barrier stops load sinking ----
  #pragma unroll
  for (int t = 0; t < NSTEP; ++t) {
    f32x4 (&cur)[2][2] = (t & 1) ? aQ : aP;
    f32x4 (&nxt)[2][2] = (t & 1) ? aP : aQ;
    if (t < NSTEP - 2) {
      #pragma unroll
      for (int m = 0; m < 2; ++m) {
        nxt[m][0] = *(const f32x4*)(keyrow + m * 16 * ENC + (t + 1) * 32);
        nxt[m][1] = *(const f32x4*)(keyrow + m * 16 * ENC + (t + 1) * 32 + 4);
      }
    } else if (t == NSTEP - 2) {
      // conv-tap A: A16[row][kk] = prev[b*T + row + kk - 15], kk<31, else 0
      #pragma unroll
      for (int m = 0; m < 2; ++m)
        #pragma unroll
        for (int h = 0; h < 2; ++h)
          #pragma unroll
          for (int j = 0; j < 4; ++j) {
            int kk = grp * 8 + h * 4 + j;
            int pos = row0 + m * 16 + rsel + kk - 15;
            nxt[m][h][j] = (kk < 31 && pos >= 0 && pos < T_LEN) ? prev[b * T_LEN + pos] : 0.f;
          }
    }
    __builtin_amdgcn_sched_barrier(0);   // pin prefetch issue above the compute
    bf16x8 af[2];
    #pragma unroll
    for (int m = 0; m < 2; ++m)
      #pragma unroll
      for (int j = 0; j < 4; ++j) {
        af[m][j]     = f2bf_fast(cur[m][0][j]);
        af[m][4 + j] = f2bf_fast(cur[m][1][j]);
      }
    const unsigned short* Bt = &Bsh[t * 4096];
    #pragma unroll
    for (int n = 0; n < 8; ++n) {
      bf16x8 bf = *(const bf16x8*)(Bt + n * 512 + lane * 8);
      acc[0][n] = __builtin_amdgcn_mfma_f32_16x16x32_bf16(af[0], bf, acc[0][n], 0, 0, 0);
      acc[1][n] = __builtin_amdgcn_mfma_f32_16x16x32_bf16(af[1], bf, acc[1][n], 0, 0, 0);
    }
  }

  // ---- epilogue: scores (wave-local, full 128 cols) ----
  float psum[2][4];
  #pragma unroll
  for (int m = 0; m < 2; ++m)
    #pragma unroll
    for (int i = 0; i < 4; ++i) psum[m][i] = 0.f;
  #pragma unroll
  for (int n = 0; n < 8; ++n) {
    int c = n * 16 + rsel;
    float pqv = pq[b * ATT + c];
    float vv = Vv[c];
    #pragma unroll
    for (int m = 0; m < 2; ++m)
      #pragma unroll
      for (int i = 0; i < 4; ++i)
        psum[m][i] += vv * fast_tanh(acc[m][n][i] + pqv);
  }
  #pragma unroll
  for (int m = 0; m < 2; ++m)
    #pragma unroll
    for (int i = 0; i < 4; ++i) {
      float v = psum[m][i];
      v += __shfl_xor(v, 1, 64);
      v += __shfl_xor(v, 2, 64);
      v += __shfl_xor(v, 4, 64);
      v += __shfl_xor(v, 8, 64);
      psum[m][i] = v;
    }
  if (rsel == 0) {
    #pragma unroll
    for (int m = 0; m < 2; ++m)
      #pragma unroll
      for (int i = 0; i < 4; ++i) {
        int r = w * 32 + m * 16 + grp * 4 + i;
        int gr = b * T_LEN + trow0 + r;
        float e = (mask[gr] == 0) ? 0.f : __expf(psum[m][i]);
        wout[gr] = e;        // unnormalized; finalize scales
        e_vals[r] = e;
      }
  }
  __syncthreads();

  if (tid < 64) {
    float v = e_vals[tid] + e_vals[tid + 64] + e_vals[tid + 128] + e_vals[tid + 192];
    #pragma unroll
    for (int off = 32; off; off >>= 1) v += __shfl_xor(v, off, 64);
    if (tid == 0) dpart[bid] = v;
  }

  // ---- partial context: 512 threads = one col each, coalesced rows, L2/L3-hot ----
  {
    float c = 0.f;
    const float* kb = keys + ((size_t)b * T_LEN + trow0) * ENC + tid;
    #pragma unroll 16
    for (int r = 0; r < BM; ++r)
      c += e_vals[r] * kb[(size_t)r * ENC];
    cpart[(size_t)bid * ENC + tid] = c;
  }
}

// ---------------- finalize: normalize weights + reduce context partials
__global__ __launch_bounds__(256) void lsa_finalize(
    const float* __restrict__ dpart, const float* __restrict__ cpart,
    float* __restrict__ out) {
  int b = blockIdx.x, tid = threadIdx.x;
  float d = 0.f;
  #pragma unroll
  for (int i = 0; i < NTB; ++i) d += dpart[b * NTB + i];
  float inv = 1.f / d;
  for (int e = tid; e < ENC; e += 256) {
    float c = 0.f;
    #pragma unroll
    for (int i = 0; i < NTB; ++i) c += cpart[((size_t)(b * NTB + i)) * ENC + e];
    out[b * ENC + e] = c * inv;
  }
  float* wrow = out + NB * ENC + (size_t)b * T_LEN;
  for (int t = tid; t < T_LEN; t += 256) wrow[t] *= inv;
}

extern "C" void kernel_launch(void* const* d_in, const int* in_sizes, int n_in,
                              void* d_out, int out_size, void* d_ws, size_t ws_size,
                              hipStream_t stream) {
  const float* query  = (const float*)d_in[0];
  const float* keys   = (const float*)d_in[1];
  const float* prev   = (const float*)d_in[2];
  const int*   mask   = (const int*)d_in[3];
  const float* W1     = (const float*)d_in[4];
  const float* W2     = (const float*)d_in[5];
  const float* V      = (const float*)d_in[6];
  const float* convw  = (const float*)d_in[7];
  const float* ldense = (const float*)d_in[8];
  float* out = (float*)d_out;

  char* ws = (char*)d_ws;
  unsigned short* Bl = (unsigned short*)ws;                       // 139264 B
  float* pq    = (float*)(ws + 139264);                           // 32768 B
  float* dpart = (float*)(ws + 139264 + 32768);                   // 4096 B (512 used)
  float* cpart = (float*)(ws + 139264 + 32768 + 4096);            // 1 MB

  prep<<<dim3(192), dim3(128), 0, stream>>>(query, W2, W1, convw, ldense, pq, Bl);
  lsa_main<<<dim3(NB * NTB), dim3(512), 0, stream>>>(keys, prev, mask, Bl, pq, V,
                                                     out + NB * ENC, dpart, cpart);
  lsa_finalize<<<dim3(NB), dim3(256), 0, stream>>>(dpart, cpart, out);
}